// Round 7
// baseline (243.063 us; speedup 1.0000x reference)
//
#include <hip/hip_runtime.h>

// Problem constants (MultiHeadAttention_9397388443950)
#define B_   2
#define S_   1024
#define SP_  1024
#define L_   2048      // SP + S
#define E_   2048
#define H_   16
#define HD_  128
#define N3_  6144      // 3*E
#define M_   2048      // B*S
#define SCALE_ 0.08838834764831845f   // 1/sqrt(128)

typedef _Float16 f16x8 __attribute__((ext_vector_type(8)));
typedef _Float16 f16x4 __attribute__((ext_vector_type(4)));
typedef _Float16 f16x2 __attribute__((ext_vector_type(2)));
typedef float    f32x4 __attribute__((ext_vector_type(4)));

#define MFMA16(a,b,c) __builtin_amdgcn_mfma_f32_16x16x32_f16(a,b,c,0,0,0)

__device__ __forceinline__ void gload16(const void* g, void* l) {
  __builtin_amdgcn_global_load_lds(
      (const __attribute__((address_space(1))) void*)g,
      (__attribute__((address_space(3))) void*)l, 16, 0, 0);
}

#define SBAR0 __builtin_amdgcn_sched_barrier(0)
#define BARRIER do { SBAR0; __builtin_amdgcn_s_barrier(); SBAR0; } while (0)

// ------- merged f32->fp16 convert (x, Wqkv, Wout) + RoPE cos/sin table -------
__global__ __launch_bounds__(256) void k_cvtall(const float* __restrict__ x,
                                                const float* __restrict__ wq,
                                                const float* __restrict__ wo,
                                                _Float16* __restrict__ xh,
                                                _Float16* __restrict__ wh,
                                                _Float16* __restrict__ woh,
                                                float2* __restrict__ cs) {
  int t = blockIdx.x * 256 + threadIdx.x;       // 2,621,440 cvt granules + cs tail
  if (t >= 2621440) {                           // cos/sin table: 131072 entries
    int u = t - 2621440;
    int pos = u >> 7, d = u & 127;
    float inv = exp2f(-(float)(d & 63) * (13.287712379549449f / 64.0f));
    float ang = (float)(SP_ + pos) * inv;
    float s, c;
    sincosf(ang, &s, &c);
    cs[u] = make_float2(c, s);
    return;
  }
  const float* src; _Float16* dst; int off;
  if (t < 524288)       { src = x;  dst = xh;  off = t; }
  else if (t < 2097152) { src = wq; dst = wh;  off = t - 524288; }
  else                  { src = wo; dst = woh; off = t - 2097152; }
  const float4* p = (const float4*)src + (size_t)off * 2;
  float4 a = p[0], b = p[1];
  f16x8 o;
  o[0]=(_Float16)a.x; o[1]=(_Float16)a.y; o[2]=(_Float16)a.z; o[3]=(_Float16)a.w;
  o[4]=(_Float16)b.x; o[5]=(_Float16)b.y; o[6]=(_Float16)b.z; o[7]=(_Float16)b.w;
  *((f16x8*)dst + off) = o;
}

// ---------------- past_key -> Kc rows [0,SP) ----------------
__global__ __launch_bounds__(256) void k_pastk(const float* __restrict__ pk,
                                               _Float16* __restrict__ Kc) {
  int t = blockIdx.x * 256 + threadIdx.x;
  int d8 = t & 15; int rest = t >> 4;
  int pos = rest & 1023; rest >>= 10;
  int h = rest & 15; int b = rest >> 4;
  const float* src = pk + ((size_t)(b * SP_ + pos) * H_ + h) * HD_ + d8 * 8;
  float4 a = *(const float4*)src, c4 = *(const float4*)(src + 4);
  f16x8 o;
  o[0]=(_Float16)a.x;  o[1]=(_Float16)a.y;  o[2]=(_Float16)a.z;  o[3]=(_Float16)a.w;
  o[4]=(_Float16)c4.x; o[5]=(_Float16)c4.y; o[6]=(_Float16)c4.z; o[7]=(_Float16)c4.w;
  *(f16x8*)(Kc + ((size_t)(b * H_ + h) * L_ + pos) * HD_ + d8 * 8) = o;
}

// ---------------- past_value -> Vt (transpose) ----------------
__global__ __launch_bounds__(256) void k_pastv(const float* __restrict__ pv,
                                               _Float16* __restrict__ Vt) {
  __shared__ _Float16 tile[64][72];
  int bh = blockIdx.x; int b = bh >> 4, h = bh & 15;
  int p0 = blockIdx.y * 64, dd0 = blockIdx.z * 64;
  for (int e = threadIdx.x; e < 4096; e += 256) {
    int p = e >> 6, d = e & 63;
    tile[p][d] = (_Float16)pv[((size_t)(b * SP_ + p0 + p) * H_ + h) * HD_ + dd0 + d];
  }
  __syncthreads();
  for (int e = threadIdx.x; e < 4096; e += 256) {
    int d = e >> 6, p = e & 63;
    Vt[((size_t)bh * HD_ + dd0 + d) * L_ + p0 + p] = tile[p][d];
  }
}

// ========= GEMM-8phase QKV: 256x192 tile, grid 256 (all CUs), 8 waves =======
// Waves 4x2: wave = 64 rows x 96 cols -> acc[4][6], 12 MFMA x 4 even phases.
// A: K-half slots [256][32] x4 (xg swizzle). B: full K-tile [192][64] x2 dbuf,
// granule swizzle lp^(row&7). Ledger: stage {ph1:B(T+1)=3, ph2:A0(T+2)=2,
// ph4:A1(T+2)=2}; end-of-T vmcnt(4) retires through B(T+1). Slot races:
// B(T+1)->opposite parity; A0(T+2) after la0's last read (ph1); A1(T+2)
// after la1's last read (ph3); barrier between in all cases.
__global__ __launch_bounds__(512, 2) void k_gemm8(const _Float16* __restrict__ A,
                                                  const _Float16* __restrict__ Bw,
                                                  const float2* __restrict__ cs,
                                                  _Float16* __restrict__ Qh,
                                                  _Float16* __restrict__ Kc,
                                                  _Float16* __restrict__ Vt) {
  __shared__ _Float16 SH[57344];                // 112 KB ring; epilogue reuses 100 KB
  const int tid = threadIdx.x, w = tid >> 6, lane = tid & 63;
  const int r = lane & 15, g = lane >> 4;
  const int wr = w >> 1, wc = w & 1;            // 4 x 2 wave grid
  const int K = E_;
  const int NT = K >> 6;                        // 32
  const int nwg = gridDim.x, flat = blockIdx.x, cpx = nwg >> 3;
  const int swz = (flat & 7) * cpx + (flat >> 3);
  const int m0 = (swz >> 5) * 256, n0 = (swz & 31) * 192;

  _Float16* const LAp = SH;                     // 4 x 8192  (A K-half slots)
  _Float16* const LBp = SH + 32768;             // 2 x 12288 (B K-tile slots)

  auto stageA = [&](int Ts, int kk) {           // 2 loads/wave
    if (Ts >= NT) return;
    _Float16* slot = LAp + ((Ts & 1) * 2 + kk) * 8192;
    int kt = (Ts << 6) + (kk << 5);
#pragma unroll
    for (int j = 0; j < 2; j++) {
      int chunk = j * 8 + w;
      int gi = chunk * 64 + lane;
      int row = gi >> 2;
      int cg = (gi & 3) ^ ((gi >> 3) & 3);
      gload16(A + (size_t)(m0 + row) * K + kt + cg * 8,
              slot + (size_t)chunk * 512);
    }
  };
  auto stageB = [&](int Ts) {                   // 3 loads/wave
    if (Ts >= NT) return;
    _Float16* slot = LBp + (Ts & 1) * 12288;
    int kt = Ts << 6;
#pragma unroll
    for (int j = 0; j < 3; j++) {
      int chunk = j * 8 + w;
      int gi = chunk * 64 + lane;
      int row = gi >> 3;
      int lpl = gi & 7;
      gload16(Bw + (size_t)(n0 + row) * K + kt + ((lpl ^ (row & 7)) << 3),
              slot + (size_t)chunk * 512);
    }
  };

  f32x4 acc[4][6] = {};
  f16x8 af[4], bf[3];

  // prologue: A0,B,A1 of t0 + A0,A1 of t1 = 11 loads/wave; retire t0 (7)
  stageA(0, 0); stageB(0); stageA(0, 1); stageA(1, 0); stageA(1, 1);
  asm volatile("s_waitcnt vmcnt(4)" ::: "memory");
  BARRIER;

  for (int T = 0; T < NT; ++T) {
    const _Float16* la0 = LAp + ((T & 1) * 2 + 0) * 8192;
    const _Float16* la1 = LAp + ((T & 1) * 2 + 1) * 8192;
    const _Float16* lb  = LBp + (T & 1) * 12288;
    // ---- phase 1: af(la0) + bf kk0 nf0-2; stage B(T+1) ----
#pragma unroll
    for (int mf = 0; mf < 4; mf++) {
      int row = wr * 64 + mf * 16 + r;
      af[mf] = *(const f16x8*)(la0 + row * 32 + (g ^ ((r >> 1) & 3)) * 8);
    }
#pragma unroll
    for (int nf = 0; nf < 3; nf++) {
      int row = wc * 96 + nf * 16 + r;
      bf[nf] = *(const f16x8*)(lb + row * 64 + ((g) ^ (row & 7)) * 8);
    }
    stageB(T + 1);
    BARRIER;
    __builtin_amdgcn_s_setprio(1);
#pragma unroll
    for (int mf = 0; mf < 4; mf++)
#pragma unroll
      for (int nf = 0; nf < 3; nf++)
        acc[mf][nf] = MFMA16(af[mf], bf[nf], acc[mf][nf]);
    __builtin_amdgcn_s_setprio(0);
    BARRIER;
    // ---- phase 2: bf kk0 nf3-5; stage A0(T+2) ----
#pragma unroll
    for (int nf = 0; nf < 3; nf++) {
      int row = wc * 96 + (nf + 3) * 16 + r;
      bf[nf] = *(const f16x8*)(lb + row * 64 + ((g) ^ (row & 7)) * 8);
    }
    stageA(T + 2, 0);
    BARRIER;
    __builtin_amdgcn_s_setprio(1);
#pragma unroll
    for (int mf = 0; mf < 4; mf++)
#pragma unroll
      for (int nf = 0; nf < 3; nf++)
        acc[mf][nf + 3] = MFMA16(af[mf], bf[nf], acc[mf][nf + 3]);
    __builtin_amdgcn_s_setprio(0);
    BARRIER;
    // ---- phase 3: af(la1) + bf kk1 nf0-2 (no stage) ----
#pragma unroll
    for (int mf = 0; mf < 4; mf++) {
      int row = wr * 64 + mf * 16 + r;
      af[mf] = *(const f16x8*)(la1 + row * 32 + (g ^ ((r >> 1) & 3)) * 8);
    }
#pragma unroll
    for (int nf = 0; nf < 3; nf++) {
      int row = wc * 96 + nf * 16 + r;
      bf[nf] = *(const f16x8*)(lb + row * 64 + ((4 + g) ^ (row & 7)) * 8);
    }
    BARRIER;
    __builtin_amdgcn_s_setprio(1);
#pragma unroll
    for (int mf = 0; mf < 4; mf++)
#pragma unroll
      for (int nf = 0; nf < 3; nf++)
        acc[mf][nf] = MFMA16(af[mf], bf[nf], acc[mf][nf]);
    __builtin_amdgcn_s_setprio(0);
    BARRIER;
    // ---- phase 4: bf kk1 nf3-5; stage A1(T+2); vmcnt ----
#pragma unroll
    for (int nf = 0; nf < 3; nf++) {
      int row = wc * 96 + (nf + 3) * 16 + r;
      bf[nf] = *(const f16x8*)(lb + row * 64 + ((4 + g) ^ (row & 7)) * 8);
    }
    stageA(T + 2, 1);
    BARRIER;
    __builtin_amdgcn_s_setprio(1);
#pragma unroll
    for (int mf = 0; mf < 4; mf++)
#pragma unroll
      for (int nf = 0; nf < 3; nf++)
        acc[mf][nf + 3] = MFMA16(af[mf], bf[nf], acc[mf][nf + 3]);
    __builtin_amdgcn_s_setprio(0);
    if (T < NT - 2) asm volatile("s_waitcnt vmcnt(4)" ::: "memory");
    else            asm volatile("s_waitcnt vmcnt(0)" ::: "memory");
    BARRIER;
  }

  // ===== fused epilogue: acc -> SH[256][200] -> RoPE(Q/K) / transpose(V) ====
#pragma unroll
  for (int mf = 0; mf < 4; mf++)
#pragma unroll
    for (int nf = 0; nf < 6; nf++)
#pragma unroll
      for (int q = 0; q < 4; q++) {
        float v = acc[mf][nf][q];
        float vp = __shfl_xor(v, 1);
        if (!(r & 1)) {
          int row = wr * 64 + mf * 16 + g * 4 + q;
          int col = wc * 96 + nf * 16 + r;
          f16x2 pk2; pk2[0] = (_Float16)v; pk2[1] = (_Float16)vp;
          *(f16x2*)&SH[row * 200 + col] = pk2;
        }
      }
  __syncthreads();

  const int bq = m0 >> 10, ib = m0 & 1023;
  int cQK = 4096 - n0; cQK = cQK < 0 ? 0 : (cQK > 192 ? 192 : cQK);
  const int nc8 = cQK >> 3;                     // 24, 8, or 0
  const int chunksQK = 256 * nc8;
  for (int cc = 0; cc < 12; cc++) {             // RoPE region (Q/K cols)
    int cid = cc * 512 + tid;
    if (cid >= chunksQK) break;
    int row = (nc8 == 24) ? (cid / 24) : (cid >> 3);
    int col = (cid - row * nc8) * 8;
    int abscol = n0 + col;
    int seg = abscol >> 11;
    int h = (abscol >> 7) & 15, dd = abscol & 127;
    int i = ib + row;
    f16x8 v = *(const f16x8*)&SH[row * 200 + col];
    const float2* cp = cs + (size_t)i * 128 + dd;
    f16x8 o;
#pragma unroll
    for (int j = 0; j < 4; j++) {
      float e  = (float)v[2 * j], od = (float)v[2 * j + 1];
      float2 c0 = cp[2 * j], c1 = cp[2 * j + 1];
      float e2 = e * c0.x - od * c0.y;
      float o2 = od * c1.x + e * c1.y;
      if (seg == 0) { e2 *= SCALE_; o2 *= SCALE_; }
      o[2 * j] = (_Float16)e2; o[2 * j + 1] = (_Float16)o2;
    }
    if (seg == 0)
      *(f16x8*)(Qh + ((size_t)(bq * H_ + h) * S_ + i) * HD_ + dd) = o;
    else
      *(f16x8*)(Kc + ((size_t)(bq * H_ + h) * L_ + SP_ + i) * HD_ + dd) = o;
  }
  const int cV = 192 - cQK;
  if (cV > 0) {
    const int chunksV = 32 * cV;
    for (int cc = 0; cc < 12; cc++) {           // V region (transpose)
      int cid = cc * 512 + tid;
      if (cid >= chunksV) break;
      int d = cid >> 5, i8 = cid & 31;
      int i0 = i8 * 8;
      int col = cQK + d;
      int abscol = n0 + col;
      int h = (abscol >> 7) & 15, dd = abscol & 127;
      f16x8 v;
#pragma unroll
      for (int k = 0; k < 8; k++) v[k] = SH[(i0 + k) * 200 + col];
      *(f16x8*)(Vt + ((size_t)(bq * H_ + h) * HD_ + dd) * L_ + SP_ + ib + i0) = v;
    }
  }
}

// ======= out-proj: 8-phase 256x256 split-K x4, atomic-f32 accumulate ========
__global__ __launch_bounds__(512, 2) void k_gemm8o(const _Float16* __restrict__ A,
                                                   const _Float16* __restrict__ Bw,
                                                   float* __restrict__ Cf) {
  __shared__ _Float16 LA[4][8192];
  __shared__ _Float16 LB[4][8192];
  const int tid = threadIdx.x, w = tid >> 6, lane = tid & 63;
  const int r = lane & 15, g = lane >> 4;
  const int wr = w >> 2, wc = w & 3;
  const int xg = g ^ ((r >> 1) & 3);
  const int nwg = gridDim.x, flat = blockIdx.x, cpx = nwg >> 3;   // 256, 32
  const int swz = (flat & 7) * cpx + (flat >> 3);
  const int mn = swz & 63, ks = swz >> 6;
  const int m0 = (mn >> 3) * 256, n0 = (mn & 7) * 256;
  const int ko = ks * 512;
  const int K = E_, N = E_;
  const int NT = 8;

  auto stage = [&](int hidx) {
    if (hidx >= 4 * NT) return;
    int Ts = hidx >> 2, kind = hidx & 3;
    int kk = kind >> 1, isB = kind & 1;
    const _Float16* src = isB ? Bw : A;
    int rb = isB ? n0 : m0;
    _Float16* slot = (isB ? &LB[0][0] : &LA[0][0]) + ((Ts & 1) * 2 + kk) * 8192;
    int kt = ko + (Ts << 6) + (kk << 5);
#pragma unroll
    for (int j = 0; j < 2; j++) {
      int chunk = j * 8 + w;
      int gi = chunk * 64 + lane;
      int row = gi >> 2;
      int cg = (gi & 3) ^ ((gi >> 3) & 3);
      gload16(src + (size_t)(rb + row) * K + kt + cg * 8,
              slot + (size_t)chunk * 512);
    }
  };

  f32x4 acc[8][4] = {};
  f16x8 af[8], bf0, bf1;

#pragma unroll
  for (int h = 0; h < 7; h++) stage(h);
  asm volatile("s_waitcnt vmcnt(6)" ::: "memory");
  BARRIER;

  for (int T = 0; T < NT; ++T) {
    const int d = (T & 1) * 2;
    const _Float16* la0 = &LA[d][0];
    const _Float16* lb0 = &LB[d][0];
    const _Float16* la1 = &LA[d + 1][0];
    const _Float16* lb1 = &LB[d + 1][0];
#pragma unroll
    for (int mf = 0; mf < 8; mf++)
      af[mf] = *(const f16x8*)(la0 + (wr * 128 + mf * 16 + r) * 32 + xg * 8);
    bf0 = *(const f16x8*)(lb0 + (wc * 64 + r) * 32 + xg * 8);
    bf1 = *(const f16x8*)(lb0 + (wc * 64 + 16 + r) * 32 + xg * 8);
    stage(4 * T + 7);
    BARRIER;
    __builtin_amdgcn_s_setprio(1);
#pragma unroll
    for (int mf = 0; mf < 8; mf++) acc[mf][0] = MFMA16(af[mf], bf0, acc[mf][0]);
#pragma unroll
    for (int mf = 0; mf < 8; mf++) acc[mf][1] = MFMA16(af[mf], bf1, acc[mf][1]);
    __builtin_amdgcn_s_setprio(0);
    BARRIER;
    bf0 = *(const f16x8*)(lb0 + (wc * 64 + 32 + r) * 32 + xg * 8);
    bf1 = *(const f16x8*)(lb0 + (wc * 64 + 48 + r) * 32 + xg * 8);
    stage(4 * T + 8);
    BARRIER;
    __builtin_amdgcn_s_setprio(1);
#pragma unroll
    for (int mf = 0; mf < 8; mf++) acc[mf][2] = MFMA16(af[mf], bf0, acc[mf][2]);
#pragma unroll
    for (int mf = 0; mf < 8; mf++) acc[mf][3] = MFMA16(af[mf], bf1, acc[mf][3]);
    __builtin_amdgcn_s_setprio(0);
    BARRIER;
#pragma unroll
    for (int mf = 0; mf < 8; mf++)
      af[mf] = *(const f16x8*)(la1 + (wr * 128 + mf * 16 + r) * 32 + xg * 8);
    bf0 = *(const f16x8*)(lb1 + (wc * 64 + r) * 32 + xg * 8);
    bf1 = *(const f16x8*)(lb1 + (wc * 64 + 16 + r) * 32 + xg * 8);
    stage(4 * T + 9);
    BARRIER;
    __builtin_amdgcn_s_setprio(1);
#pragma unroll
    for (int mf = 0; mf < 8; mf++) acc[mf][0] = MFMA16(af[mf], bf0, acc[mf][0]);
#pragma unroll
    for (int mf = 0; mf < 8; mf++) acc[mf][1] = MFMA16(af[mf], bf1, acc[mf][1]);
    __builtin_amdgcn_s_setprio(0);
    BARRIER;
    bf0 = *(const f16x8*)(lb1 + (wc * 64 + 32 + r) * 32 + xg * 8);
    bf1 = *(const f16x8*)(lb1 + (wc * 64 + 48 + r) * 32 + xg * 8);
    stage(4 * T + 10);
    BARRIER;
    __builtin_amdgcn_s_setprio(1);
#pragma unroll
    for (int mf = 0; mf < 8; mf++) acc[mf][2] = MFMA16(af[mf], bf0, acc[mf][2]);
#pragma unroll
    for (int mf = 0; mf < 8; mf++) acc[mf][3] = MFMA16(af[mf], bf1, acc[mf][3]);
    __builtin_amdgcn_s_setprio(0);
    if (T < NT - 2) asm volatile("s_waitcnt vmcnt(6)" ::: "memory");
    else            asm volatile("s_waitcnt vmcnt(0)" ::: "memory");
    BARRIER;
  }

#pragma unroll
  for (int mf = 0; mf < 8; mf++)
#pragma unroll
    for (int nf = 0; nf < 4; nf++)
#pragma unroll
      for (int q = 0; q < 4; q++) {
        size_t idx = (size_t)(m0 + wr * 128 + mf * 16 + g * 4 + q) * N
                   + n0 + wc * 64 + nf * 16 + r;
        unsafeAtomicAdd(&Cf[idx], acc[mf][nf][q]);
      }
}

// -------- Flash attention: R4 4-wave structure + counted-vmcnt dbuf --------
// LDS 72 KB -> 2 blocks/CU preserved. Stage chunk c+1 then vmcnt(8)
// (8 gloads/wave/chunk); raw barriers (no vmcnt(0) drain per chunk).
__global__ __launch_bounds__(256) void k_attn(const _Float16* __restrict__ Qh,
                                              const _Float16* __restrict__ Kc,
                                              const _Float16* __restrict__ Vt,
                                              _Float16* __restrict__ Oh) {
  __shared__ _Float16 Kl[2][64 * 128];
  __shared__ _Float16 Vl[2][128 * 64];
  __shared__ _Float16 Pl[4][16 * 64];
  const int tid = threadIdx.x, w = tid >> 6, lane = tid & 63;
  const int r = lane & 15, g = lane >> 4;
  const int bh = blockIdx.x, tile = blockIdx.y;
  const int i0 = tile * 64, q0 = i0 + w * 16;
  const _Float16* Kbase = Kc + (size_t)bh * L_ * HD_;
  const _Float16* Vbase = Vt + (size_t)bh * HD_ * L_;
  f16x8 qf[4];
  {
    const _Float16* qp = Qh + ((size_t)bh * S_ + q0 + r) * HD_ + g * 8;
#pragma unroll
    for (int kk = 0; kk < 4; kk++) qf[kk] = *(const f16x8*)(qp + kk * 32);
  }
  f32x4 acc[8] = {};
  float mrun = -1e30f, lrun = 0.f;
  const int lim = SP_ + q0 + r;
  const int nch = (SP_ + i0 + 64) >> 6;

  auto stageKV = [&](int c, int buf) {
    const int c0 = c << 6;
#pragma unroll
    for (int it = 0; it < 4; it++) {
      int bg = it * 256 + w * 64;
      int gr = bg + lane;
      int krow = gr >> 4, kc = ((gr & 15) ^ (krow & 7)) * 8;
      gload16(Kbase + (size_t)(c0 + krow) * HD_ + kc, &Kl[buf][bg * 8]);
      int vrow = gr >> 3, vc = ((gr & 7) ^ (vrow & 7)) * 8;
      gload16(Vbase + (size_t)vrow * L_ + c0 + vc, &Vl[buf][bg * 8]);
    }
  };

  stageKV(0, 0);
  for (int c = 0; c < nch; c++) {
    const int c0 = c << 6;
    const int buf = c & 1;
    if (c + 1 < nch) {
      stageKV(c + 1, buf ^ 1);
      asm volatile("s_waitcnt vmcnt(8)" ::: "memory");
    } else {
      asm volatile("s_waitcnt vmcnt(0)" ::: "memory");
    }
    BARRIER;
    f32x4 sc[4] = {};
#pragma unroll
    for (int mf = 0; mf < 4; mf++)
#pragma unroll
      for (int kk = 0; kk < 4; kk++) {
        int row = mf * 16 + r;
        int gran = (g + kk * 4) ^ (row & 7);
        f16x8 kf = *(const f16x8*)&Kl[buf][row * 128 + gran * 8];
        sc[mf] = MFMA16(kf, qf[kk], sc[mf]);
      }
    float p[4][4];
    float rmax = -1e30f;
#pragma unroll
    for (int mf = 0; mf < 4; mf++)
#pragma unroll
      for (int jj = 0; jj < 4; jj++) {
        float v = sc[mf][jj];
        int kp = c0 + mf * 16 + g * 4 + jj;
        if (kp > lim) v = -1e30f;
        p[mf][jj] = v;
        rmax = fmaxf(rmax, v);
      }
    rmax = fmaxf(rmax, __shfl_xor(rmax, 16));
    rmax = fmaxf(rmax, __shfl_xor(rmax, 32));
    float mnew = fmaxf(mrun, rmax);
    float scale = __expf(mrun - mnew);
    float psum = 0.f;
#pragma unroll
    for (int mf = 0; mf < 4; mf++)
#pragma unroll
      for (int jj = 0; jj < 4; jj++) {
        float e = __expf(p[mf][jj] - mnew);
        p[mf][jj] = e;
        psum += e;
      }
    psum += __shfl_xor(psum, 16);
    psum += __shfl_xor(psum, 32);
    lrun = lrun * scale + psum;
    mrun = mnew;
#pragma unroll
    for (int mf = 0; mf < 4; mf++) {
      f16x4 ph;
#pragma unroll
      for (int jj = 0; jj < 4; jj++) ph[jj] = (_Float16)p[mf][jj];
      int g16 = (mf * 2 + (g >> 1)) ^ (r & 7);
      *(f16x4*)&Pl[w][r * 64 + g16 * 8 + (g & 1) * 4] = ph;
    }
    float scj[4];
#pragma unroll
    for (int jj = 0; jj < 4; jj++) scj[jj] = __shfl(scale, g * 4 + jj);
#pragma unroll
    for (int nf = 0; nf < 8; nf++)
#pragma unroll
      for (int jj = 0; jj < 4; jj++) acc[nf][jj] *= scj[jj];
#pragma unroll
    for (int kk = 0; kk < 2; kk++) {
      f16x8 pf = *(const f16x8*)&Pl[w][r * 64 + ((g + kk * 4) ^ (r & 7)) * 8];
#pragma unroll
      for (int nf = 0; nf < 8; nf++) {
        int vrow = nf * 16 + r;
        int gran = (g + kk * 4) ^ (vrow & 7);
        f16x8 vf = *(const f16x8*)&Vl[buf][vrow * 64 + gran * 8];
        acc[nf] = MFMA16(pf, vf, acc[nf]);
      }
    }
    BARRIER;
  }
  float inv[4];
#pragma unroll
  for (int jj = 0; jj < 4; jj++) inv[jj] = 1.f / __shfl(lrun, g * 4 + jj);
  const int b = bh >> 4, h = bh & 15;
#pragma unroll
  for (int nf = 0; nf < 8; nf++)
#pragma unroll
    for (int jj = 0; jj < 4; jj++) {
      size_t idx = (size_t)(b * S_ + i0 + w * 16 + g * 4 + jj) * E_ + h * HD_ + nf * 16 + r;
      Oh[idx] = (_Float16)(acc[nf][jj] * inv[jj]);
    }
}

extern "C" void kernel_launch(void* const* d_in, const int* in_sizes, int n_in,
                              void* d_out, int out_size, void* d_ws, size_t ws_size,
                              hipStream_t stream) {
  (void)in_sizes; (void)n_in; (void)ws_size;
  const float* x    = (const float*)d_in[0];
  const float* Wqkv = (const float*)d_in[1];
  const float* Wout = (const float*)d_in[2];
  const float* pk   = (const float*)d_in[3];
  const float* pv   = (const float*)d_in[4];

  char* ws = (char*)d_ws;
  _Float16* Xh   = (_Float16*)(ws);               // 8.39MB (reused as Oh)
  _Float16* Wh   = (_Float16*)(ws + 8388608);     // 25.2MB
  _Float16* Qhb  = (_Float16*)(ws + 33554432);    // 8.39MB
  _Float16* Kcb  = (_Float16*)(ws + 41943040);    // 16.8MB
  _Float16* Vtb  = (_Float16*)(ws + 58720256);    // 16.8MB
  float2*   cs   = (float2*)  (ws + 75497472);    // 1MB
  _Float16* Woh  = (_Float16*)(ws + 76546048);    // 8.39MB  (total ~85MB)
  _Float16* Ohb  = Xh;

  hipMemsetAsync(d_out, 0, (size_t)out_size * sizeof(float), stream);
  k_cvtall<<<10752, 256, 0, stream>>>(x, Wqkv, Wout, Xh, Wh, Woh, cs);
  k_pastk <<<2048,  256, 0, stream>>>(pk, Kcb);
  k_pastv <<<dim3(32, 16, 2), 256, 0, stream>>>(pv, Vtb);
  k_gemm8 <<<256, 512, 0, stream>>>(Xh, Wh, cs, Qhb, Kcb, Vtb);
  k_attn  <<<dim3(32, 16), 256, 0, stream>>>(Qhb, Kcb, Vtb, Ohb);
  k_gemm8o<<<256, 512, 0, stream>>>(Ohb, Woh, (float*)d_out);
}